// Round 2
// baseline (302.228 us; speedup 1.0000x reference)
//
#include <hip/hip_runtime.h>
#include <hip/hip_bf16.h>
#include <math.h>

// ---------------------------------------------------------------------------
// Workspace layout (float offsets)
// ---------------------------------------------------------------------------
constexpr size_t OFF_QW1  = 0;
constexpr size_t OFF_QW2  = OFF_QW1 + 162;
constexpr size_t OFF_QB2  = OFF_QW2 + 648;
constexpr size_t OFF_QW3  = OFF_QB2 + 12;
constexpr size_t OFF_QB3  = OFF_QW3 + 1944;
constexpr size_t OFF_QW4  = OFF_QB3 + 18;
constexpr size_t OFF_QB4  = OFF_QW4 + 2916;
constexpr size_t OFF_QW5  = OFF_QB4 + 18;
constexpr size_t OFF_QB5  = OFF_QW5 + 2916;
constexpr size_t OFF_QF1  = OFF_QB5 + 18;
constexpr size_t OFF_QFB1 = OFF_QF1 + 19440;
constexpr size_t OFF_QF2  = OFF_QFB1 + 120;
constexpr size_t OFF_QFB2 = OFF_QF2 + 10080;
constexpr size_t OFF_QF3  = OFF_QFB2 + 84;
constexpr size_t OFF_OUT1 = OFF_QF3 + 756;                       // [256,6,79,79]
constexpr size_t OFF_OUT2 = OFF_OUT1 + (size_t)256*6*79*79;      // [256,12,38,38]
constexpr size_t OFF_OUT3 = OFF_OUT2 + (size_t)256*12*38*38;     // [256,18,18,18]
constexpr size_t OFF_OUT4 = OFF_OUT3 + (size_t)256*18*18*18;     // [256,18,8,8]
constexpr size_t OFF_OUT5 = OFF_OUT4 + (size_t)256*18*8*8;       // [256,162]
constexpr size_t OFF_FC1  = OFF_OUT5 + (size_t)256*162;          // [256,120]
constexpr size_t OFF_FC2  = OFF_FC1 + (size_t)256*120;           // [256,84]

// ---------------------------------------------------------------------------
// Weight + bias fake-quantization (one block per weight tensor)
// ---------------------------------------------------------------------------
__global__ void quant_prep(
    const float* w1, const float* w2, const float* b2,
    const float* w3, const float* b3, const float* w4, const float* b4,
    const float* w5, const float* b5, const float* fw1, const float* fb1,
    const float* fw2, const float* fb2, const float* fw3,
    const float* s1, const float* s2, const float* s3,
    const float* s4, const float* s5, const float* s6,
    float* ws)
{
    const int b = blockIdx.x;
    const float* W[8]  = {w1, w2, w3, w4, w5, fw1, fw2, fw3};
    const int    NW[8] = {162, 648, 1944, 2916, 2916, 19440, 10080, 756};
    float* WQ[8] = {ws+OFF_QW1, ws+OFF_QW2, ws+OFF_QW3, ws+OFF_QW4,
                    ws+OFF_QW5, ws+OFF_QF1, ws+OFF_QF2, ws+OFF_QF3};
    const float* B[8]  = {nullptr, b2, b3, b4, b5, fb1, fb2, nullptr};
    const int    NB[8] = {0, 12, 18, 18, 18, 120, 84, 0};
    float* BQ[8] = {nullptr, ws+OFF_QB2, ws+OFF_QB3, ws+OFF_QB4,
                    ws+OFF_QB5, ws+OFF_QFB1, ws+OFF_QFB2, nullptr};
    const float* SP[8] = {nullptr, s1, s2, s3, s4, s5, s6, nullptr};

    const float* w = W[b];
    const int nw = NW[b];

    float mx = 0.0f;
    for (int i = threadIdx.x; i < nw; i += blockDim.x)
        mx = fmaxf(mx, fabsf(w[i]));
    __shared__ float red[256];
    red[threadIdx.x] = mx;
    __syncthreads();
    for (int s = 128; s > 0; s >>= 1) {
        if ((int)threadIdx.x < s)
            red[threadIdx.x] = fmaxf(red[threadIdx.x], red[threadIdx.x + s]);
        __syncthreads();
    }
    const float sw = red[0] / 3.0f;

    float* wq = WQ[b];
    for (int i = threadIdx.x; i < nw; i += blockDim.x) {
        float q = rintf(w[i] / sw);
        q = fminf(fmaxf(q, -3.0f), 3.0f);
        wq[i] = q * sw;
    }
    if (B[b] != nullptr) {
        const float sb = sw * (SP[b][0] / 15.0f);
        for (int i = threadIdx.x; i < NB[b]; i += blockDim.x)
            BQ[b][i] = rintf(B[b][i] / sb) * sb;
    }
}

// ---------------------------------------------------------------------------
// Fused conv3x3(VALID) [+bias] + quant_relu(s) + maxpool2, register-blocked.
// Block = (r-block of RB pooled rows, image n). LDS holds 2*RB+2 input rows
// of all CIN channels (row length padded to WINP; pad/OOB values only feed
// discarded outputs). Thread = (co, xg, ry): computes TX pooled cols of one
// pooled row for one output channel. Row-streamed: per (channel, input row)
// read 2*TX+2 floats (broadcast across the COUT lanes sharing xg -> no bank
// conflicts), FMA into 2 conv-rows x 2*TX accumulators.
// quant_relu and +bias are monotone => pool first, then bias+quant once.
// ---------------------------------------------------------------------------
template<int CIN, int COUT, int HIN, int WIN, int HPOOL, int WPOOL,
         int TX, int XG, int RB, int THREADS, bool HAS_BIAS>
__global__ __launch_bounds__(THREADS)
void conv_stage(const float* __restrict__ in,
                const float* __restrict__ qw,
                const float* __restrict__ qb,
                const float* __restrict__ s_act,
                float* __restrict__ out)
{
    constexpr int ROWS = 2 * RB + 2;
    constexpr int WINP = 2 * TX * XG + 2;   // padded LDS row length
    constexpr int TOTAL = COUT * XG * RB;

    __shared__ float lds[CIN][ROWS][WINP];

    const int r0 = blockIdx.x * RB;
    const int n  = blockIdx.y;

    // cooperative fill (cols >= WIN and rows >= HIN stay garbage: only feed
    // discarded outputs)
    const float* inN = in + (size_t)n * CIN * HIN * WIN;
    for (int idx = threadIdx.x; idx < CIN * ROWS * WIN; idx += THREADS) {
        const int c   = idx / (ROWS * WIN);
        const int rem = idx - c * (ROWS * WIN);
        const int rr  = rem / WIN;
        const int col = rem - rr * WIN;
        const int grow = 2 * r0 + rr;
        if (grow < HIN)
            lds[c][rr][col] = inN[((size_t)c * HIN + grow) * WIN + col];
    }
    __syncthreads();

    const float step = s_act[0] / 15.0f;

    for (int o = threadIdx.x; o < TOTAL; o += THREADS) {
        const int co = o % COUT;
        const int t  = o / COUT;
        const int xg = t % XG;
        const int ry = t / XG;

        float acc0[2 * TX], acc1[2 * TX];
#pragma unroll
        for (int i = 0; i < 2 * TX; ++i) { acc0[i] = 0.f; acc1[i] = 0.f; }

        const float* wco = qw + co * CIN * 9;
        const int rbase = 2 * ry;
        const int cbase = 2 * TX * xg;

        for (int c = 0; c < CIN; ++c) {
            float wv[9];
#pragma unroll
            for (int i = 0; i < 9; ++i) wv[i] = wco[c * 9 + i];

#pragma unroll
            for (int rr = 0; rr < 4; ++rr) {
                float row[2 * TX + 2];
#pragma unroll
                for (int i = 0; i < 2 * TX + 2; ++i)
                    row[i] = lds[c][rbase + rr][cbase + i];

                if (rr <= 2) {          // contributes to conv row 0, kr = rr
#pragma unroll
                    for (int kc = 0; kc < 3; ++kc)
#pragma unroll
                        for (int xx = 0; xx < 2 * TX; ++xx)
                            acc0[xx] = fmaf(row[xx + kc], wv[rr * 3 + kc], acc0[xx]);
                }
                if (rr >= 1) {          // contributes to conv row 1, kr = rr-1
#pragma unroll
                    for (int kc = 0; kc < 3; ++kc)
#pragma unroll
                        for (int xx = 0; xx < 2 * TX; ++xx)
                            acc1[xx] = fmaf(row[xx + kc], wv[(rr - 1) * 3 + kc], acc1[xx]);
                }
            }
        }

        const float bias = HAS_BIAS ? qb[co] : 0.0f;
        const int r = r0 + ry;
        if (r < HPOOL) {
            float* orow = out + (((size_t)n * COUT + co) * HPOOL + r) * WPOOL;
#pragma unroll
            for (int x = 0; x < TX; ++x) {
                const int px = xg * TX + x;
                float m = fmaxf(fmaxf(acc0[2 * x], acc0[2 * x + 1]),
                                fmaxf(acc1[2 * x], acc1[2 * x + 1]));
                float v = fmaxf(m + bias, 0.0f);
                float q = rintf(v / step);
                q = fminf(fmaxf(q, 0.0f), 15.0f);
                if (px < WPOOL) orow[px] = q * step;
            }
        }
    }
}

// ---------------------------------------------------------------------------
// FC: out[n][m] = dot(in[n], w[m]) [+ bias] [quant_relu]
// ---------------------------------------------------------------------------
template<int K, int M, bool HAS_BIAS, bool DO_QUANT>
__global__ void fc_stage(const float* __restrict__ in,
                         const float* __restrict__ qw,
                         const float* __restrict__ qb,
                         const float* __restrict__ s_act,
                         float* __restrict__ out, int N)
{
    const int idx = blockIdx.x * blockDim.x + threadIdx.x;
    if (idx >= N * M) return;
    const int n = idx / M;
    const int m = idx - n * M;

    const float* irow = in + (size_t)n * K;
    const float* wrow = qw + (size_t)m * K;
    float acc = 0.0f;
    for (int k = 0; k < K; ++k)
        acc += irow[k] * wrow[k];

    if (HAS_BIAS) acc += qb[m];
    if (DO_QUANT) {
        const float step = s_act[0] / 15.0f;
        float q = rintf(fmaxf(acc, 0.0f) / step);
        q = fminf(fmaxf(q, 0.0f), 15.0f);
        acc = q * step;
    }
    out[idx] = acc;
}

// ---------------------------------------------------------------------------
extern "C" void kernel_launch(void* const* d_in, const int* in_sizes, int n_in,
                              void* d_out, int out_size, void* d_ws, size_t ws_size,
                              hipStream_t stream)
{
    const float* x   = (const float*)d_in[0];
    const float* w1  = (const float*)d_in[1];
    const float* w2  = (const float*)d_in[2];
    const float* b2  = (const float*)d_in[3];
    const float* w3  = (const float*)d_in[4];
    const float* b3  = (const float*)d_in[5];
    const float* w4  = (const float*)d_in[6];
    const float* b4  = (const float*)d_in[7];
    const float* w5  = (const float*)d_in[8];
    const float* b5  = (const float*)d_in[9];
    const float* fw1 = (const float*)d_in[10];
    const float* fb1 = (const float*)d_in[11];
    const float* fw2 = (const float*)d_in[12];
    const float* fb2 = (const float*)d_in[13];
    const float* fw3 = (const float*)d_in[14];
    const float* s1  = (const float*)d_in[15];
    const float* s2  = (const float*)d_in[16];
    const float* s3  = (const float*)d_in[17];
    const float* s4  = (const float*)d_in[18];
    const float* s5  = (const float*)d_in[19];
    const float* s6  = (const float*)d_in[20];
    const float* s7  = (const float*)d_in[21];

    float* ws = (float*)d_ws;
    float* out = (float*)d_out;

    quant_prep<<<8, 256, 0, stream>>>(w1, w2, b2, w3, b3, w4, b4, w5, b5,
                                      fw1, fb1, fw2, fb2, fw3,
                                      s1, s2, s3, s4, s5, s6, ws);

    // stage 1: [256,3,160,160] -> [256,6,79,79]
    // TX=5, XG=16, RB=2, THREADS=192 (=6*16*2, one o-iter), LDS 3*6*162*4 = 11.7KB
    conv_stage<3, 6, 160, 160, 79, 79, 5, 16, 2, 192, false>
        <<<dim3(40, 256), 192, 0, stream>>>(x, ws + OFF_QW1, nullptr, s1, ws + OFF_OUT1);

    // stage 2: -> [256,12,38,38]; TX=5, XG=8, RB=2, THREADS=192 (=12*8*2)
    conv_stage<6, 12, 79, 79, 38, 38, 5, 8, 2, 192, true>
        <<<dim3(19, 256), 192, 0, stream>>>(ws + OFF_OUT1, ws + OFF_QW2, ws + OFF_QB2, s2, ws + OFF_OUT2);

    // stage 3: -> [256,18,18,18]; TX=6, XG=3, RB=3, THREADS=192 (TOTAL=162)
    conv_stage<12, 18, 38, 38, 18, 18, 6, 3, 3, 192, true>
        <<<dim3(6, 256), 192, 0, stream>>>(ws + OFF_OUT2, ws + OFF_QW3, ws + OFF_QB3, s3, ws + OFF_OUT3);

    // stage 4: -> [256,18,8,8]; TX=4, XG=2, RB=4, THREADS=192 (TOTAL=144)
    conv_stage<18, 18, 18, 18, 8, 8, 4, 2, 4, 192, true>
        <<<dim3(2, 256), 192, 0, stream>>>(ws + OFF_OUT3, ws + OFF_QW4, ws + OFF_QB4, s4, ws + OFF_OUT4);

    // stage 5: -> [256,18,3,3] == [256,162]; TX=3, XG=1, RB=3, THREADS=64 (TOTAL=54)
    conv_stage<18, 18, 8, 8, 3, 3, 3, 1, 3, 64, true>
        <<<dim3(1, 256), 64, 0, stream>>>(ws + OFF_OUT4, ws + OFF_QW5, ws + OFF_QB5, s5, ws + OFF_OUT5);

    // fc1: [256,162] -> [256,120]
    fc_stage<162, 120, true, true>
        <<<(256 * 120 + 255) / 256, 256, 0, stream>>>(ws + OFF_OUT5, ws + OFF_QF1, ws + OFF_QFB1, s6, ws + OFF_FC1, 256);

    // fc2: -> [256,84]
    fc_stage<120, 84, true, true>
        <<<(256 * 84 + 255) / 256, 256, 0, stream>>>(ws + OFF_FC1, ws + OFF_QF2, ws + OFF_QFB2, s7, ws + OFF_FC2, 256);

    // fc3: -> [256,9]
    fc_stage<84, 9, false, false>
        <<<(256 * 9 + 255) / 256, 256, 0, stream>>>(ws + OFF_FC2, ws + OFF_QF3, nullptr, nullptr, out, 256);
}

// Round 3
// 229.024 us; speedup vs baseline: 1.3196x; 1.3196x over previous
//
#include <hip/hip_runtime.h>
#include <hip/hip_bf16.h>
#include <math.h>

// ---------------------------------------------------------------------------
// Workspace layout (float offsets). Intermediates use padded row strides
// (multiple of 4 floats) so fills/stores are float4. OUT3 aliases OUT1
// (OUT1 is dead once conv3 runs) to keep total ws under the round-2 footprint.
// ---------------------------------------------------------------------------
constexpr size_t OFF_QW1  = 0;
constexpr size_t OFF_QW2  = OFF_QW1 + 162;
constexpr size_t OFF_QB2  = OFF_QW2 + 648;
constexpr size_t OFF_QW3  = OFF_QB2 + 12;
constexpr size_t OFF_QB3  = OFF_QW3 + 1944;
constexpr size_t OFF_QW4  = OFF_QB3 + 18;
constexpr size_t OFF_QB4  = OFF_QW4 + 2916;
constexpr size_t OFF_QW5  = OFF_QB4 + 18;
constexpr size_t OFF_QB5  = OFF_QW5 + 2916;
constexpr size_t OFF_QF1  = OFF_QB5 + 18;     // transposed [162][120]
constexpr size_t OFF_QFB1 = OFF_QF1 + 19440;
constexpr size_t OFF_QF2  = OFF_QFB1 + 120;   // transposed [120][84]
constexpr size_t OFF_QFB2 = OFF_QF2 + 10080;
constexpr size_t OFF_QF3  = OFF_QFB2 + 84;    // transposed [84][9]
constexpr size_t OFF_WEND = OFF_QF3 + 756;    // = 39132, %4 == 0
constexpr size_t OFF_OUT1 = OFF_WEND;                         // [256][6][79][80]
constexpr size_t OFF_OUT2 = OFF_OUT1 + (size_t)256*6*79*80;   // [256][12][38][40]
constexpr size_t OFF_OUT3 = OFF_OUT1;                         // [256][18][18][20] (alias)

// ---------------------------------------------------------------------------
// Weight + bias fake-quantization. FC weights written TRANSPOSED ([K][M]) for
// coalesced reads in the fused tail kernel.
// ---------------------------------------------------------------------------
__global__ void quant_prep(
    const float* w1, const float* w2, const float* b2,
    const float* w3, const float* b3, const float* w4, const float* b4,
    const float* w5, const float* b5, const float* fw1, const float* fb1,
    const float* fw2, const float* fb2, const float* fw3,
    const float* s1, const float* s2, const float* s3,
    const float* s4, const float* s5, const float* s6,
    float* ws)
{
    const int b = blockIdx.x;
    const float* W[8]  = {w1, w2, w3, w4, w5, fw1, fw2, fw3};
    const int    NWv[8] = {162, 648, 1944, 2916, 2916, 19440, 10080, 756};
    float* WQ[8] = {ws+OFF_QW1, ws+OFF_QW2, ws+OFF_QW3, ws+OFF_QW4,
                    ws+OFF_QW5, ws+OFF_QF1, ws+OFF_QF2, ws+OFF_QF3};
    const float* B[8]  = {nullptr, b2, b3, b4, b5, fb1, fb2, nullptr};
    const int    NB[8] = {0, 12, 18, 18, 18, 120, 84, 0};
    float* BQ[8] = {nullptr, ws+OFF_QB2, ws+OFF_QB3, ws+OFF_QB4,
                    ws+OFF_QB5, ws+OFF_QFB1, ws+OFF_QFB2, nullptr};
    const float* SP[8] = {nullptr, s1, s2, s3, s4, s5, s6, nullptr};
    const int    MM[8] = {0, 0, 0, 0, 0, 120, 84, 9};    // fc: transpose
    const int    KK[8] = {1, 1, 1, 1, 1, 162, 120, 84};

    const float* w = W[b];
    const int nw = NWv[b];

    float mx = 0.0f;
    for (int i = threadIdx.x; i < nw; i += blockDim.x)
        mx = fmaxf(mx, fabsf(w[i]));
    __shared__ float red[256];
    red[threadIdx.x] = mx;
    __syncthreads();
    for (int s = 128; s > 0; s >>= 1) {
        if ((int)threadIdx.x < s)
            red[threadIdx.x] = fmaxf(red[threadIdx.x], red[threadIdx.x + s]);
        __syncthreads();
    }
    const float sw = red[0] / 3.0f;

    float* wq = WQ[b];
    for (int i = threadIdx.x; i < nw; i += blockDim.x) {
        float q = rintf(w[i] / sw);
        q = fminf(fmaxf(q, -3.0f), 3.0f);
        const float val = q * sw;
        if (MM[b]) {
            const int m = i / KK[b];
            const int k = i - m * KK[b];
            wq[k * MM[b] + m] = val;
        } else {
            wq[i] = val;
        }
    }
    if (B[b] != nullptr) {
        const float sb = sw * (SP[b][0] / 15.0f);
        for (int i = threadIdx.x; i < NB[b]; i += blockDim.x)
            BQ[b][i] = rintf(B[b][i] / sb) * sb;
    }
}

// ---------------------------------------------------------------------------
// Fused conv3x3(VALID)+bias+quant_relu+maxpool2, register-blocked, all
// operands (input slab + weights) staged in LDS, float4 everywhere.
// Thread = (co, xg, ry): TX pooled cols x 1 pooled row x 1 out channel.
// ---------------------------------------------------------------------------
template<int CIN, int COUT, int HIN, int WSTRIDE_IN,
         int HPOOL, int WPOOL, int WSTRIDE_OUT,
         int TX, int XG, int RB, int THREADS, bool HAS_BIAS>
__global__ __launch_bounds__(THREADS)
void conv_stage(const float* __restrict__ in,
                const float* __restrict__ qw,
                const float* __restrict__ qb,
                const float* __restrict__ s_act,
                float* __restrict__ out)
{
    constexpr int ROWS = 2 * RB + 2;
    constexpr int WROW = 2 * TX * XG + 4;      // multiple of 4
    constexpr int NV   = TX / 2 + 1;           // float4 row reads
    constexpr int NW   = COUT * CIN * 9;
    constexpr int W4   = WSTRIDE_IN / 4;
    static_assert(TX % 4 == 0, "vec4 alignment");
    static_assert(WSTRIDE_IN % 4 == 0, "vec4 fill");
    static_assert(COUT * XG * RB <= THREADS, "one o-iter");
    static_assert(TX * XG == WSTRIDE_OUT, "full padded row coverage");

    __shared__ float lin[CIN][ROWS][WROW];
    __shared__ float lw[NW];
    __shared__ float lb[COUT];

    const int r0 = blockIdx.x * RB;
    const int n  = blockIdx.y;

    for (int i = threadIdx.x; i < NW; i += THREADS) lw[i] = qw[i];
    if (HAS_BIAS)
        for (int i = threadIdx.x; i < COUT; i += THREADS) lb[i] = qb[i];

    const float* inN = in + (size_t)n * CIN * HIN * WSTRIDE_IN;
    for (int idx = threadIdx.x; idx < CIN * ROWS * W4; idx += THREADS) {
        const int c   = idx / (ROWS * W4);
        const int rem = idx - c * (ROWS * W4);
        const int rr  = rem / W4;
        const int c4  = (rem - rr * W4) * 4;
        const int grow = 2 * r0 + rr;
        if (grow < HIN) {
            const float4 v = *(const float4*)&inN[((size_t)c * HIN + grow) * WSTRIDE_IN + c4];
            *(float4*)&lin[c][rr][c4] = v;
        }
    }
    __syncthreads();

    const int o = threadIdx.x;
    if (o < COUT * XG * RB) {
        const int co = o % COUT;
        const int t  = o / COUT;
        const int xg = t % XG;
        const int ry = t / XG;
        const int cbase = 2 * TX * xg;

        float acc0[2 * TX], acc1[2 * TX];
#pragma unroll
        for (int i = 0; i < 2 * TX; ++i) { acc0[i] = 0.f; acc1[i] = 0.f; }

        for (int c = 0; c < CIN; ++c) {
            float wv[9];
#pragma unroll
            for (int i = 0; i < 9; ++i) wv[i] = lw[(co * CIN + c) * 9 + i];

#pragma unroll
            for (int rr = 0; rr < 4; ++rr) {
                float4 rv[NV];
#pragma unroll
                for (int v = 0; v < NV; ++v)
                    rv[v] = *(const float4*)&lin[c][2 * ry + rr][cbase + 4 * v];
                const float* row = (const float*)rv;  // 2*TX+4 floats

                if (rr < 3) {
#pragma unroll
                    for (int kc = 0; kc < 3; ++kc)
#pragma unroll
                        for (int xx = 0; xx < 2 * TX; ++xx)
                            acc0[xx] = fmaf(row[xx + kc], wv[rr * 3 + kc], acc0[xx]);
                }
                if (rr >= 1) {
#pragma unroll
                    for (int kc = 0; kc < 3; ++kc)
#pragma unroll
                        for (int xx = 0; xx < 2 * TX; ++xx)
                            acc1[xx] = fmaf(row[xx + kc], wv[(rr - 1) * 3 + kc], acc1[xx]);
                }
            }
        }

        const int r = r0 + ry;
        if (r < HPOOL) {
            const float bias = HAS_BIAS ? lb[co] : 0.0f;
            const float step = s_act[0] / 15.0f;
            float* orow = out + (((size_t)n * COUT + co) * HPOOL + r) * WSTRIDE_OUT;
#pragma unroll
            for (int g = 0; g < TX / 4; ++g) {
                float4 st;
#pragma unroll
                for (int j = 0; j < 4; ++j) {
                    const int x  = 4 * g + j;
                    const int px = TX * xg + x;
                    float m = fmaxf(fmaxf(acc0[2 * x], acc0[2 * x + 1]),
                                    fmaxf(acc1[2 * x], acc1[2 * x + 1]));
                    float v = fmaxf(m + bias, 0.0f);
                    float q = rintf(v / step);
                    q = fminf(fmaxf(q, 0.0f), 15.0f);
                    ((float*)&st)[j] = (px < WPOOL) ? q * step : 0.0f;
                }
                *(float4*)&orow[TX * xg + 4 * g] = st;
            }
        }
    }
}

// ---------------------------------------------------------------------------
// Fused tail: stage4 conv + stage5 conv + fc1 + fc2 + fc3. One block / image.
// All activations and conv weights live in LDS; fc weights read coalesced
// (transposed) from global (L2-resident, 89 KB total).
// ---------------------------------------------------------------------------
__global__ __launch_bounds__(256)
void tail_stage(const float* __restrict__ in3,   // [256][18][18][20]
                const float* __restrict__ ws,
                const float* __restrict__ s4, const float* __restrict__ s5,
                const float* __restrict__ s6, const float* __restrict__ s7,
                float* __restrict__ out)
{
    __shared__ float A[18][18][20];   // stage-3 output slab
    __shared__ float W4[2916], W5[2916];
    __shared__ float B4[18], B5[18];
    __shared__ float O4[18][8][8];
    __shared__ float A5[162], A6[120], A7[84];

    const int n   = blockIdx.x;
    const int tid = threadIdx.x;

    const float4* src = (const float4*)(in3 + (size_t)n * 6480);
    float4* dstA = (float4*)&A[0][0][0];
    for (int i = tid; i < 1620; i += 256) dstA[i] = src[i];
    const float* qw4 = ws + OFF_QW4;
    const float* qw5 = ws + OFF_QW5;
    for (int i = tid; i < 2916; i += 256) { W4[i] = qw4[i]; W5[i] = qw5[i]; }
    if (tid < 18) { B4[tid] = (ws + OFF_QB4)[tid]; B5[tid] = (ws + OFF_QB5)[tid]; }
    __syncthreads();

    // ---- stage 4: [18,18,18] -> [18,8,8] ----
    {
        const float step = s4[0] / 15.0f;
        for (int o = tid; o < 18 * 64; o += 256) {
            const int co = o >> 6;
            const int r  = (o >> 3) & 7;
            const int x  = o & 7;
            float a00 = 0.f, a01 = 0.f, a10 = 0.f, a11 = 0.f;
            for (int c = 0; c < 18; ++c) {
                float win[4][4];
#pragma unroll
                for (int rr = 0; rr < 4; ++rr)
#pragma unroll
                    for (int cc = 0; cc < 4; ++cc)
                        win[rr][cc] = A[c][2 * r + rr][2 * x + cc];
                const float* wp = &W4[(co * 18 + c) * 9];
#pragma unroll
                for (int kr = 0; kr < 3; ++kr)
#pragma unroll
                    for (int kc = 0; kc < 3; ++kc) {
                        const float wv = wp[kr * 3 + kc];
                        a00 = fmaf(win[kr    ][kc    ], wv, a00);
                        a01 = fmaf(win[kr    ][kc + 1], wv, a01);
                        a10 = fmaf(win[kr + 1][kc    ], wv, a10);
                        a11 = fmaf(win[kr + 1][kc + 1], wv, a11);
                    }
            }
            float m = fmaxf(fmaxf(a00, a01), fmaxf(a10, a11));
            float v = fmaxf(m + B4[co], 0.0f);
            float q = rintf(v / step);
            q = fminf(fmaxf(q, 0.0f), 15.0f);
            O4[co][r][x] = q * step;
        }
    }
    __syncthreads();

    // ---- stage 5: [18,8,8] -> [18,3,3] = A5[162] ----
    {
        const float step = s5[0] / 15.0f;
        if (tid < 162) {
            const int co = tid / 9;
            const int rem = tid - co * 9;
            const int r = rem / 3;
            const int x = rem - r * 3;
            float a00 = 0.f, a01 = 0.f, a10 = 0.f, a11 = 0.f;
            for (int c = 0; c < 18; ++c) {
                float win[4][4];
#pragma unroll
                for (int rr = 0; rr < 4; ++rr)
#pragma unroll
                    for (int cc = 0; cc < 4; ++cc)
                        win[rr][cc] = O4[c][2 * r + rr][2 * x + cc];
                const float* wp = &W5[(co * 18 + c) * 9];
#pragma unroll
                for (int kr = 0; kr < 3; ++kr)
#pragma unroll
                    for (int kc = 0; kc < 3; ++kc) {
                        const float wv = wp[kr * 3 + kc];
                        a00 = fmaf(win[kr    ][kc    ], wv, a00);
                        a01 = fmaf(win[kr    ][kc + 1], wv, a01);
                        a10 = fmaf(win[kr + 1][kc    ], wv, a10);
                        a11 = fmaf(win[kr + 1][kc + 1], wv, a11);
                    }
            }
            float m = fmaxf(fmaxf(a00, a01), fmaxf(a10, a11));
            float v = fmaxf(m + B5[co], 0.0f);
            float q = rintf(v / step);
            q = fminf(fmaxf(q, 0.0f), 15.0f);
            A5[tid] = q * step;   // flatten order = (co, r, x) = reference reshape
        }
    }
    __syncthreads();

    // ---- fc1: [162] -> [120], quant s6 ----
    {
        const float* w = ws + OFF_QF1;    // [162][120]
        if (tid < 120) {
            float acc = 0.f;
#pragma unroll 6
            for (int k = 0; k < 162; ++k)
                acc = fmaf(A5[k], w[k * 120 + tid], acc);
            acc += (ws + OFF_QFB1)[tid];
            const float step = s6[0] / 15.0f;
            float q = rintf(fmaxf(acc, 0.0f) / step);
            q = fminf(fmaxf(q, 0.0f), 15.0f);
            A6[tid] = q * step;
        }
    }
    __syncthreads();

    // ---- fc2: [120] -> [84], quant s7 ----
    {
        const float* w = ws + OFF_QF2;    // [120][84]
        if (tid < 84) {
            float acc = 0.f;
#pragma unroll 6
            for (int k = 0; k < 120; ++k)
                acc = fmaf(A6[k], w[k * 84 + tid], acc);
            acc += (ws + OFF_QFB2)[tid];
            const float step = s7[0] / 15.0f;
            float q = rintf(fmaxf(acc, 0.0f) / step);
            q = fminf(fmaxf(q, 0.0f), 15.0f);
            A7[tid] = q * step;
        }
    }
    __syncthreads();

    // ---- fc3: [84] -> [9] ----
    {
        const float* w = ws + OFF_QF3;    // [84][9]
        if (tid < 9) {
            float acc = 0.f;
#pragma unroll 6
            for (int k = 0; k < 84; ++k)
                acc = fmaf(A7[k], w[k * 9 + tid], acc);
            out[(size_t)n * 9 + tid] = acc;
        }
    }
}

// ---------------------------------------------------------------------------
extern "C" void kernel_launch(void* const* d_in, const int* in_sizes, int n_in,
                              void* d_out, int out_size, void* d_ws, size_t ws_size,
                              hipStream_t stream)
{
    const float* x   = (const float*)d_in[0];
    const float* w1  = (const float*)d_in[1];
    const float* w2  = (const float*)d_in[2];
    const float* b2  = (const float*)d_in[3];
    const float* w3  = (const float*)d_in[4];
    const float* b3  = (const float*)d_in[5];
    const float* w4  = (const float*)d_in[6];
    const float* b4  = (const float*)d_in[7];
    const float* w5  = (const float*)d_in[8];
    const float* b5  = (const float*)d_in[9];
    const float* fw1 = (const float*)d_in[10];
    const float* fb1 = (const float*)d_in[11];
    const float* fw2 = (const float*)d_in[12];
    const float* fb2 = (const float*)d_in[13];
    const float* fw3 = (const float*)d_in[14];
    const float* s1  = (const float*)d_in[15];
    const float* s2  = (const float*)d_in[16];
    const float* s3  = (const float*)d_in[17];
    const float* s4  = (const float*)d_in[18];
    const float* s5  = (const float*)d_in[19];
    const float* s6  = (const float*)d_in[20];
    const float* s7  = (const float*)d_in[21];

    float* ws = (float*)d_ws;
    float* out = (float*)d_out;

    quant_prep<<<8, 256, 0, stream>>>(w1, w2, b2, w3, b3, w4, b4, w5, b5,
                                      fw1, fb1, fw2, fb2, fw3,
                                      s1, s2, s3, s4, s5, s6, ws);

    // stage 1: [256,3,160,160] -> [256,6,79,80p]; TX=8 XG=10 RB=2, 128 thr
    conv_stage<3, 6, 160, 160, 79, 79, 80, 8, 10, 2, 128, false>
        <<<dim3(40, 256), 128, 0, stream>>>(x, ws + OFF_QW1, nullptr, s1, ws + OFF_OUT1);

    // stage 2: -> [256,12,38,40p]; TX=8 XG=5 RB=2, 128 thr
    conv_stage<6, 12, 79, 80, 38, 38, 40, 8, 5, 2, 128, true>
        <<<dim3(19, 256), 128, 0, stream>>>(ws + OFF_OUT1, ws + OFF_QW2, ws + OFF_QB2, s2, ws + OFF_OUT2);

    // stage 3: -> [256,18,18,20p]; TX=4 XG=5 RB=2, 192 thr
    conv_stage<12, 18, 38, 40, 18, 18, 20, 4, 5, 2, 192, true>
        <<<dim3(9, 256), 192, 0, stream>>>(ws + OFF_OUT2, ws + OFF_QW3, ws + OFF_QB3, s3, ws + OFF_OUT3);

    // fused tail: stage4 + stage5 + fc1 + fc2 + fc3, one block per image
    tail_stage<<<256, 256, 0, stream>>>(ws + OFF_OUT3, ws, s4, s5, s6, s7, out);
}